// Round 1
// 82.223 us; speedup vs baseline: 1.0133x; 1.0133x over previous
//
#include <hip/hip_runtime.h>
#include <math.h>

#define NPTS   4096
#define NB     8
#define TILE   128                        // i-points per block (2 per thread)
#define NWAVES 16
#define BLK    (NWAVES * 64)              // 1024 threads
#define JCHUNK (NPTS / NWAVES)            // 256
#define INV_H2 (1.0f / (0.03f * 0.03f))   // 1/h^2
#define INFV   3.0e38f

__device__ __forceinline__ float med3f(float a, float b, float c) {
#if defined(__has_builtin)
#if __has_builtin(__builtin_amdgcn_fmed3f)
  return __builtin_amdgcn_fmed3f(a, b, c);
#else
  return fminf(c, fmaxf(a, b));
#endif
#else
  return fminf(c, fmaxf(a, b));
#endif
}

// Scan LDS points [lo,hi) for TWO i-points per thread.
// t = sq_j - 2*p_i.p_j  (sq_i folded out: top-4 selection is invariant to +sq_i,
// applied after the merge). 3 FMA per i per j, then 4-op sorted insert per i.
// CHECK: 0 = none, 1 = exclude j==self_lo from lo-list, 2 = exclude j==self_hi from hi-list.
template <int CHECK>
__device__ __forceinline__ void scan2(const float4* __restrict__ sP, int lo, int hi,
                                      int self_lo, int self_hi,
                                      float mxl, float myl, float mzl,
                                      float mxh, float myh, float mzh,
                                      float& a0, float& a1, float& a2, float& a3,
                                      float& b0, float& b1, float& b2, float& b3) {
#pragma unroll 8
  for (int j = lo; j < hi; ++j) {
    float4 q = sP[j];                     // ds_read_b128, wave-uniform addr (broadcast)
    float tl = fmaf(mzl, q.z, q.w);       // q.w = ||p_j||^2
    tl = fmaf(myl, q.y, tl);
    tl = fmaf(mxl, q.x, tl);
    float th = fmaf(mzh, q.z, q.w);
    th = fmaf(myh, q.y, th);
    th = fmaf(mxh, q.x, th);
    if (CHECK == 1) tl = (j == self_lo) ? INFV : tl;
    if (CHECK == 2) th = (j == self_hi) ? INFV : th;
    // sorted insert (uses previous-iteration values; 4 indep ops per list)
    a3 = med3f(a2, tl, a3);
    a2 = med3f(a1, tl, a2);
    a1 = med3f(a0, tl, a1);
    a0 = fminf(a0, tl);
    b3 = med3f(b2, th, b3);
    b2 = med3f(b1, th, b2);
    b1 = med3f(b0, th, b1);
    b0 = fminf(b0, th);
  }
}

// lowest-4 (ascending) of two ascending 4-lists. Safe when outputs alias inputs.
__device__ __forceinline__ void merge4(float a0, float a1, float a2, float a3,
                                       float b0, float b1, float b2, float b3,
                                       float& o0, float& o1, float& o2, float& o3) {
  float L0 = fminf(a0, b3), L1 = fminf(a1, b2), L2 = fminf(a2, b1), L3 = fminf(a3, b0);
  float e0 = fminf(L0, L2), e2 = fmaxf(L0, L2);
  float e1 = fminf(L1, L3), e3 = fmaxf(L1, L3);
  o0 = fminf(e0, e1); o1 = fmaxf(e0, e1);
  o2 = fminf(e2, e3); o3 = fmaxf(e2, e3);
}

__global__ __launch_bounds__(BLK)
void repulsion_kernel(const float* __restrict__ pc, float* __restrict__ out) {
  __shared__ float4 sP[NPTS];                  // 64 KB: x,y,z,||p||^2
  __shared__ float4 cand[NWAVES * TILE];       // 32 KB: per-wave partial 4-lists

  const int blk  = blockIdx.x;
  const int b    = blk >> 5;      // / (NPTS/TILE) = /32
  const int tile = blk & 31;
  const int tid  = threadIdx.x;
  const float* base = pc + (size_t)b * NPTS * 3;
  const float4* pcv = (const float4*)base;     // 3072 float4 per batch (16B-aligned)

  // Stage batch into LDS: each thread loads 3 float4 -> 4 points (1024 groups total).
  {
    const int g = tid;                         // g < 1024 == NPTS/4
    float4 a = pcv[3 * g + 0];
    float4 c = pcv[3 * g + 1];
    float4 e = pcv[3 * g + 2];
    float x0 = a.x, y0 = a.y, z0 = a.z;
    float x1 = a.w, y1 = c.x, z1 = c.y;
    float x2 = c.z, y2 = c.w, z2 = e.x;
    float x3 = e.y, y3 = e.z, z3 = e.w;
    sP[4 * g + 0] = make_float4(x0, y0, z0, fmaf(x0, x0, fmaf(y0, y0, z0 * z0)));
    sP[4 * g + 1] = make_float4(x1, y1, z1, fmaf(x1, x1, fmaf(y1, y1, z1 * z1)));
    sP[4 * g + 2] = make_float4(x2, y2, z2, fmaf(x2, x2, fmaf(y2, y2, z2 * z2)));
    sP[4 * g + 3] = make_float4(x3, y3, z3, fmaf(x3, x3, fmaf(y3, y3, z3 * z3)));
  }
  __syncthreads();

  const int w    = tid >> 6;      // wave index = j-sixteenth
  const int lane = tid & 63;
  const int self_lo = tile * TILE + lane;      // first owned i-point
  const int self_hi = self_lo + 64;            // second owned i-point

  float4 plo = sP[self_lo];
  float4 phi = sP[self_hi];
  const float mxl = -2.0f * plo.x, myl = -2.0f * plo.y, mzl = -2.0f * plo.z;
  const float mxh = -2.0f * phi.x, myh = -2.0f * phi.y, mzh = -2.0f * phi.z;

  float a0 = INFV, a1 = INFV, a2 = INFV, a3 = INFV;
  float b0 = INFV, b1 = INFV, b2 = INFV, b3 = INFV;

  const int j0 = w * JCHUNK;
  const int cs = tile >> 1;       // chunk index holding this tile's i-range
  if (w == cs) {
    const int s = j0 + ((tile & 1) << 7);      // == tile*TILE
    scan2<0>(sP, j0, s, self_lo, self_hi, mxl, myl, mzl, mxh, myh, mzh,
             a0, a1, a2, a3, b0, b1, b2, b3);
    scan2<1>(sP, s, s + 64, self_lo, self_hi, mxl, myl, mzl, mxh, myh, mzh,
             a0, a1, a2, a3, b0, b1, b2, b3);
    scan2<2>(sP, s + 64, s + 128, self_lo, self_hi, mxl, myl, mzl, mxh, myh, mzh,
             a0, a1, a2, a3, b0, b1, b2, b3);
    scan2<0>(sP, s + 128, j0 + JCHUNK, self_lo, self_hi, mxl, myl, mzl, mxh, myh, mzh,
             a0, a1, a2, a3, b0, b1, b2, b3);
  } else {
    scan2<0>(sP, j0, j0 + JCHUNK, self_lo, self_hi, mxl, myl, mzl, mxh, myh, mzh,
             a0, a1, a2, a3, b0, b1, b2, b3);
  }

  cand[w * TILE + lane]      = make_float4(a0, a1, a2, a3);   // lists for i in [0,64)
  cand[w * TILE + 64 + lane] = make_float4(b0, b1, b2, b3);   // lists for i in [64,128)
  __syncthreads();

  // Merge 16 per-wave lists per i-point; threads 0..127 (2 waves), one i each.
  if (tid < TILE) {
    float4 M = cand[tid];
    float m0 = M.x, m1 = M.y, m2 = M.z, m3 = M.w;
#pragma unroll
    for (int ww = 1; ww < NWAVES; ++ww) {
      float4 Cw = cand[ww * TILE + tid];
      merge4(m0, m1, m2, m3, Cw.x, Cw.y, Cw.z, Cw.w, m0, m1, m2, m3);
    }

    const float sqi = sP[tile * TILE + tid].w;
    float d0 = fmaxf(m0 + sqi, 0.0f);
    float d1 = fmaxf(m1 + sqi, 0.0f);
    float d2 = fmaxf(m2 + sqi, 0.0f);
    float d3 = fmaxf(m3 + sqi, 0.0f);

    float s = 0.0f;
    s -= d0 * expf(-d0 * INV_H2);
    s -= d1 * expf(-d1 * INV_H2);
    s -= d2 * expf(-d2 * INV_H2);
    s -= d3 * expf(-d3 * INV_H2);

    for (int off = 32; off > 0; off >>= 1) s += __shfl_down(s, off);
    if (lane == 0) atomicAdd(out, s);
  }
}

extern "C" void kernel_launch(void* const* d_in, const int* in_sizes, int n_in,
                              void* d_out, int out_size, void* d_ws, size_t ws_size,
                              hipStream_t stream) {
  const float* pc = (const float*)d_in[0];
  float* out = (float*)d_out;
  hipMemsetAsync(out, 0, sizeof(float), stream);
  repulsion_kernel<<<dim3(NB * (NPTS / TILE)), dim3(BLK), 0, stream>>>(pc, out);
}